// Round 8
// baseline (752.847 us; speedup 1.0000x reference)
//
#include <hip/hip_runtime.h>

#define NN 200000
#define EE 400000
#define GG 4096

// ws layout (float offsets)
#define AGG_OFF 0
#define H1_OFF  (NN * 64)              // 12,800,000
#define SE_OFF  (H1_OFF + NN * 64)     // 25,600,000 (2*GG ints)
#define CHUNK_OFF (SE_OFF + 2 * GG)    // 25,608,192 : hidden-activation buffer (200k x 128)
// CSR arrays live in the UPPER half of cbuf: only gemm n2a (after the last agg
// pass) writes past cbuf+NN*64, so they survive exactly as long as needed.
#define CSR_OFF (CHUNK_OFF + NN * 64)

#define NB1 ((NN + 1023) / 1024)       // 196 scan blocks

// ---------------- segment boundaries from sorted batch ----------------
__global__ void bounds_kernel(const int* __restrict__ batch, int* __restrict__ se) {
    int n = blockIdx.x * blockDim.x + threadIdx.x;
    if (n >= NN) return;
    int b = batch[n];
    if (n == 0 || batch[n - 1] != b) se[b] = n;                 // start
    if (n == NN - 1 || batch[n + 1] != b) se[GG + b] = n + 1;   // end
}

// ---------------- CSR build ----------------
__global__ void deg_kernel(const int* __restrict__ ei, int* __restrict__ cursor) {
    int e = blockIdx.x * blockDim.x + threadIdx.x;
    if (e >= EE) return;
    atomicAdd(cursor + ei[EE + e], 1);
}

// block-level exclusive scan, 1024 elements/block (256 thr x 4)
__global__ __launch_bounds__(256) void scan1_kernel(const int* __restrict__ deg,
                                                    int* __restrict__ rowptr,
                                                    int* __restrict__ partials) {
    __shared__ int sdata[256];
    int t = threadIdx.x;
    int base = blockIdx.x * 1024 + t * 4;
    int v[4]; int s = 0;
#pragma unroll
    for (int j = 0; j < 4; j++) {
        v[j] = (base + j < NN) ? deg[base + j] : 0;
        s += v[j];
    }
    sdata[t] = s;
    __syncthreads();
#pragma unroll
    for (int off = 1; off < 256; off <<= 1) {
        int x = (t >= off) ? sdata[t - off] : 0;
        __syncthreads();
        sdata[t] += x;
        __syncthreads();
    }
    int run = sdata[t] - s;   // exclusive prefix of this thread's chunk
#pragma unroll
    for (int j = 0; j < 4; j++) {
        if (base + j < NN) rowptr[base + j] = run;
        run += v[j];
    }
    if (t == 255) partials[blockIdx.x] = sdata[255];
}

__global__ __launch_bounds__(256) void scan2_kernel(int* __restrict__ partials) {
    __shared__ int sdata[256];
    int t = threadIdx.x;
    int p = (t < NB1) ? partials[t] : 0;
    sdata[t] = p;
    __syncthreads();
#pragma unroll
    for (int off = 1; off < 256; off <<= 1) {
        int x = (t >= off) ? sdata[t - off] : 0;
        __syncthreads();
        sdata[t] += x;
        __syncthreads();
    }
    if (t < NB1) partials[t] = sdata[t] - p;   // exclusive
}

__global__ __launch_bounds__(256) void scan3_kernel(int* __restrict__ rowptr,
                                                    const int* __restrict__ partials) {
    int t = threadIdx.x;
    int add = partials[blockIdx.x];
    int base = blockIdx.x * 1024 + t * 4;
#pragma unroll
    for (int j = 0; j < 4; j++)
        if (base + j < NN) rowptr[base + j] += add;
}

__global__ void scatter_kernel(const int* __restrict__ ei,
                               const int* __restrict__ rowptr,
                               int* __restrict__ cursor,
                               int* __restrict__ eidx) {
    int e = blockIdx.x * blockDim.x + threadIdx.x;
    if (e >= EE) return;
    int d = ei[EE + e];
    int pos = rowptr[d] + atomicAdd(cursor + d, 1);
    eidx[pos] = e;
}

// ---------------- gather aggregation, 4 nodes per wave (MLP x4) ----------------
// agg[n] = xin[n] + sum_{e in in(n)} relu(ea[e]@W + b + xin[src[e]])
// Wave = 4 nodes in lockstep; per deg-level, 4 independent load chains
// (eidx -> ei -> {ea row, x row}) are issued phase-by-phase so their
// latencies overlap. All per-node predicates are wave-uniform (SGPR branch).
#define NPW 4
__global__ __launch_bounds__(256) void agg_pass(const float* __restrict__ xin,
                                                const int* __restrict__ ei,
                                                const float* __restrict__ ea,
                                                const float* __restrict__ ew,
                                                const float* __restrict__ eb,
                                                const int* __restrict__ rowptr,
                                                const int* __restrict__ cnt,
                                                const int* __restrict__ eidx,
                                                float* __restrict__ agg) {
    const int lane = threadIdx.x & 63;
    const int wid  = threadIdx.x >> 6;
    const int nbase = (blockIdx.x * 4 + wid) * NPW;
    if (nbase >= NN) return;   // no barriers in this kernel

    float Wr[16];
#pragma unroll
    for (int k = 0; k < 16; k++) Wr[k] = ew[k * 64 + lane];   // ew: (16,64)
    const float br = eb[lane];

    int s[NPW], deg[NPW];
    float sum[NPW];
#pragma unroll
    for (int j = 0; j < NPW; j++) {
        int n = nbase + j;
        bool valid = (n < NN);
        int nc = valid ? n : (NN - 1);
        s[j]   = __builtin_amdgcn_readfirstlane(rowptr[nc]);
        deg[j] = valid ? __builtin_amdgcn_readfirstlane(cnt[nc]) : 0;
        sum[j] = valid ? xin[(size_t)nc * 64 + lane] : 0.0f;
    }

    int maxdeg = deg[0];
#pragma unroll
    for (int j = 1; j < NPW; j++) maxdeg = (deg[j] > maxdeg) ? deg[j] : maxdeg;

    for (int i = 0; i < maxdeg; i++) {
        int e[NPW], src[NPW];
        // phase 1: edge ids (4 independent loads)
#pragma unroll
        for (int j = 0; j < NPW; j++)
            e[j] = (i < deg[j]) ? __builtin_amdgcn_readfirstlane(eidx[s[j] + i]) : -1;
        // phase 2: src ids (4 independent loads)
#pragma unroll
        for (int j = 0; j < NPW; j++)
            src[j] = (e[j] >= 0) ? __builtin_amdgcn_readfirstlane(ei[e[j]]) : 0;
        // phase 3: payload loads (8 independent streams)
        float4 P0[NPW], P1[NPW], P2[NPW], P3[NPW];
        float  XV[NPW];
#pragma unroll
        for (int j = 0; j < NPW; j++) {
            if (e[j] >= 0) {
                const float4* ea4 = (const float4*)(ea + (size_t)e[j] * 16);
                P0[j] = ea4[0]; P1[j] = ea4[1]; P2[j] = ea4[2]; P3[j] = ea4[3];
                XV[j] = xin[(size_t)src[j] * 64 + lane];
            }
        }
        // phase 4: FMAs
#pragma unroll
        for (int j = 0; j < NPW; j++) {
            if (e[j] >= 0) {
                float acc = br;
                acc += P0[j].x * Wr[0];  acc += P0[j].y * Wr[1];
                acc += P0[j].z * Wr[2];  acc += P0[j].w * Wr[3];
                acc += P1[j].x * Wr[4];  acc += P1[j].y * Wr[5];
                acc += P1[j].z * Wr[6];  acc += P1[j].w * Wr[7];
                acc += P2[j].x * Wr[8];  acc += P2[j].y * Wr[9];
                acc += P2[j].z * Wr[10]; acc += P2[j].w * Wr[11];
                acc += P3[j].x * Wr[12]; acc += P3[j].y * Wr[13];
                acc += P3[j].z * Wr[14]; acc += P3[j].w * Wr[15];
                sum[j] += fmaxf(acc + XV[j], 0.0f);
            }
        }
    }

#pragma unroll
    for (int j = 0; j < NPW; j++) {
        int n = nbase + j;
        if (n < NN) agg[(size_t)n * 64 + lane] = sum[j];
    }
}

// ---------------- tiled dense layer, W staged in LDS (K-chunked), X prefetch ----
template <int K, int C, bool RELU, bool SPLITY>
__global__ __launch_bounds__(256) void gemm_kernel(const float* __restrict__ X,
                                                   const float* __restrict__ W,
                                                   const float* __restrict__ Bv,
                                                   float* __restrict__ Ylo,
                                                   float* __restrict__ Yhi,
                                                   int rows) {
    constexpr int CPT = 8, RPT = 4;
    constexpr int COLG = C / CPT;        // 8 (C=64) or 16 (C=128)
    constexpr int ROWG = 256 / COLG;     // 32 or 16
    constexpr int BR = ROWG * RPT;       // 128 or 64 rows per block
    constexpr int KC = (K < 64) ? K : 64;  // K-chunk staged in LDS (<=32 KB)

    __shared__ float Bs[KC * C];

    const int cg = threadIdx.x % COLG;
    const int rg = threadIdx.x / COLG;
    const int c0a = cg * 4;
    const int c0b = C / 2 + cg * 4;
    const int rbase = blockIdx.x * BR + rg * RPT;

    const float* xptr[RPT];
#pragma unroll
    for (int r = 0; r < RPT; r++) {
        int rr = rbase + r;
        int ri = (rr < rows) ? rr : (rows - 1);
        xptr[r] = X + (size_t)ri * K;
    }

    float acc[RPT][CPT];
    {
        const float4* ba = (const float4*)(Bv + c0a);
        const float4* bb = (const float4*)(Bv + c0b);
        float4 v0 = ba[0], v1 = bb[0];
#pragma unroll
        for (int r = 0; r < RPT; r++) {
            acc[r][0] = v0.x; acc[r][1] = v0.y; acc[r][2] = v0.z; acc[r][3] = v0.w;
            acc[r][4] = v1.x; acc[r][5] = v1.y; acc[r][6] = v1.z; acc[r][7] = v1.w;
        }
    }

    float4 a_cur[RPT], a_nxt[RPT];
#pragma unroll
    for (int r = 0; r < RPT; r++) a_cur[r] = *(const float4*)(xptr[r]);

#pragma unroll 1
    for (int kc = 0; kc < K; kc += KC) {
        __syncthreads();
        {
            const float4* wsrc = (const float4*)(W + (size_t)kc * C);
            float4* wdst = (float4*)Bs;
            for (int i = threadIdx.x; i < KC * C / 4; i += 256) wdst[i] = wsrc[i];
        }
        __syncthreads();

#pragma unroll 2
        for (int k4 = 0; k4 < KC; k4 += 4) {
            const int knext = kc + k4 + 4;
            if (knext < K) {
#pragma unroll
                for (int r = 0; r < RPT; r++)
                    a_nxt[r] = *(const float4*)(xptr[r] + knext);
            }
#pragma unroll
            for (int kk = 0; kk < 4; kk++) {
                const float4 w0 = *(const float4*)(Bs + (k4 + kk) * C + c0a);
                const float4 w1 = *(const float4*)(Bs + (k4 + kk) * C + c0b);
#pragma unroll
                for (int r = 0; r < RPT; r++) {
                    float av = (kk == 0) ? a_cur[r].x : (kk == 1) ? a_cur[r].y
                             : (kk == 2) ? a_cur[r].z : a_cur[r].w;
                    acc[r][0] += av * w0.x; acc[r][1] += av * w0.y;
                    acc[r][2] += av * w0.z; acc[r][3] += av * w0.w;
                    acc[r][4] += av * w1.x; acc[r][5] += av * w1.y;
                    acc[r][6] += av * w1.z; acc[r][7] += av * w1.w;
                }
            }
#pragma unroll
            for (int r = 0; r < RPT; r++) a_cur[r] = a_nxt[r];
        }
    }

#pragma unroll
    for (int r = 0; r < RPT; r++) {
        int rr = rbase + r;
        if (rr < rows) {
            float4 v0, v1;
            v0.x = RELU ? fmaxf(acc[r][0], 0.0f) : acc[r][0];
            v0.y = RELU ? fmaxf(acc[r][1], 0.0f) : acc[r][1];
            v0.z = RELU ? fmaxf(acc[r][2], 0.0f) : acc[r][2];
            v0.w = RELU ? fmaxf(acc[r][3], 0.0f) : acc[r][3];
            v1.x = RELU ? fmaxf(acc[r][4], 0.0f) : acc[r][4];
            v1.y = RELU ? fmaxf(acc[r][5], 0.0f) : acc[r][5];
            v1.z = RELU ? fmaxf(acc[r][6], 0.0f) : acc[r][6];
            v1.w = RELU ? fmaxf(acc[r][7], 0.0f) : acc[r][7];
            if (SPLITY) {
                *(float4*)(Ylo + (size_t)rr * 64 + c0a) = v0;
                *(float4*)(Yhi + (size_t)rr * 64 + (c0b - C / 2)) = v1;
            } else {
                *(float4*)(Ylo + (size_t)rr * C + c0a) = v0;
                *(float4*)(Ylo + (size_t)rr * C + c0b) = v1;
            }
        }
    }
}

// ---------------- head: mean-pool (via segment bounds) + 5-layer MLP ----------------
__global__ __launch_bounds__(128) void head_kernel(const float* __restrict__ hlo,
                                                   const float* __restrict__ hhi,
                                                   const int* __restrict__ se,
                                                   const float* __restrict__ usr,
                                                   const float* __restrict__ h1w, const float* __restrict__ h1b,
                                                   const float* __restrict__ h2w, const float* __restrict__ h2b,
                                                   const float* __restrict__ h3w, const float* __restrict__ h3b,
                                                   const float* __restrict__ h4w, const float* __restrict__ h4b,
                                                   const float* __restrict__ h5w, const float* __restrict__ h5b,
                                                   float* __restrict__ out) {
    int g = blockIdx.x;
    int c = threadIdx.x;
    __shared__ float z0[140];
    __shared__ float z1[128];
    __shared__ float z2[64];
    __shared__ float z3[32];
    __shared__ float z4[16];

    int s = se[g], e = se[GG + g];
    float sum = 0.0f;
    if (c < 64) {
        for (int n = s; n < e; n++) sum += hlo[(size_t)n * 64 + c];
    } else {
        for (int n = s; n < e; n++) sum += hhi[(size_t)n * 64 + (c - 64)];
    }
    float cnt = fmaxf((float)(e - s), 1.0f);
    z0[c] = sum / cnt;
    if (c < 12) z0[128 + c] = usr[g * 12 + c];
    __syncthreads();

    {
        float acc = h1b[c];
        for (int k = 0; k < 140; k++) acc += z0[k] * h1w[k * 128 + c];
        z1[c] = fmaxf(acc, 0.0f);
    }
    __syncthreads();
    if (c < 64) {
        float acc = h2b[c];
        for (int k = 0; k < 128; k++) acc += z1[k] * h2w[k * 64 + c];
        z2[c] = fmaxf(acc, 0.0f);
    }
    __syncthreads();
    if (c < 32) {
        float acc = h3b[c];
        for (int k = 0; k < 64; k++) acc += z2[k] * h3w[k * 32 + c];
        z3[c] = fmaxf(acc, 0.0f);
    }
    __syncthreads();
    if (c < 16) {
        float acc = h4b[c];
        for (int k = 0; k < 32; k++) acc += z3[k] * h4w[k * 16 + c];
        z4[c] = fmaxf(acc, 0.0f);
    }
    __syncthreads();
    if (c == 0) {
        float acc = h5b[0];
        for (int k = 0; k < 16; k++) acc += z4[k] * h5w[k];
        out[g] = acc;
    }
}

extern "C" void kernel_launch(void* const* d_in, const int* in_sizes, int n_in,
                              void* d_out, int out_size, void* d_ws, size_t ws_size,
                              hipStream_t stream) {
    const float* x    = (const float*)d_in[0];
    const int*   ei   = (const int*)d_in[1];
    const float* ea   = (const float*)d_in[2];
    const int*   batch= (const int*)d_in[3];
    const float* usr  = (const float*)d_in[4];
    const float* e1w  = (const float*)d_in[5],  *e1b  = (const float*)d_in[6];
    const float* n1w1 = (const float*)d_in[7],  *n1b1 = (const float*)d_in[8];
    const float* n1w2 = (const float*)d_in[9],  *n1b2 = (const float*)d_in[10];
    const float* e2w  = (const float*)d_in[11], *e2b  = (const float*)d_in[12];
    const float* n2w1 = (const float*)d_in[13], *n2b1 = (const float*)d_in[14];
    const float* n2w2 = (const float*)d_in[15], *n2b2 = (const float*)d_in[16];
    const float* h1w  = (const float*)d_in[17], *h1b  = (const float*)d_in[18];
    const float* h2w  = (const float*)d_in[19], *h2b  = (const float*)d_in[20];
    const float* h3w  = (const float*)d_in[21], *h3b  = (const float*)d_in[22];
    const float* h4w  = (const float*)d_in[23], *h4b  = (const float*)d_in[24];
    const float* h5w  = (const float*)d_in[25], *h5b  = (const float*)d_in[26];

    float* w    = (float*)d_ws;
    float* agg  = w + AGG_OFF;
    float* h1   = w + H1_OFF;
    int*   se   = (int*)(w + SE_OFF);
    float* cbuf = w + CHUNK_OFF;

    int* rowptr   = (int*)(w + CSR_OFF);
    int* cursor   = rowptr + NN;
    int* eidx     = cursor + NN;
    int* partials = eidx + EE;

    hipMemsetAsync(se, 0, (size_t)GG * 2 * sizeof(int), stream);
    hipMemsetAsync(cursor, 0, (size_t)NN * sizeof(int), stream);

    bounds_kernel<<<(NN + 255) / 256, 256, 0, stream>>>(batch, se);

    // ---- CSR build (shared by both layers) ----
    deg_kernel<<<(EE + 255) / 256, 256, 0, stream>>>(ei, cursor);
    scan1_kernel<<<NB1, 256, 0, stream>>>(cursor, rowptr, partials);
    scan2_kernel<<<1, 256, 0, stream>>>(partials);
    scan3_kernel<<<NB1, 256, 0, stream>>>(rowptr, partials);
    hipMemsetAsync(cursor, 0, (size_t)NN * sizeof(int), stream);
    scatter_kernel<<<(EE + 255) / 256, 256, 0, stream>>>(ei, rowptr, cursor, eidx);
    // after scatter, cursor[n] == deg[n]

    // ---- layer 1 ----
    agg_pass<<<(NN + 4 * NPW - 1) / (4 * NPW), 256, 0, stream>>>(
        x, ei, ea, e1w, e1b, rowptr, cursor, eidx, agg);
    gemm_kernel<64, 64, true, false><<<(NN + 127) / 128, 256, 0, stream>>>(
        agg, n1w1, n1b1, cbuf, nullptr, NN);
    gemm_kernel<64, 64, true, false><<<(NN + 127) / 128, 256, 0, stream>>>(
        cbuf, n1w2, n1b2, h1, nullptr, NN);

    // ---- layer 2 ---- (CSR intact: n1a only wrote cbuf[0:NN*64])
    agg_pass<<<(NN + 4 * NPW - 1) / (4 * NPW), 256, 0, stream>>>(
        h1, ei, ea, e2w, e2b, rowptr, cursor, eidx, agg);
    gemm_kernel<64, 128, true, false><<<(NN + 63) / 64, 256, 0, stream>>>(
        agg, n2w1, n2b1, cbuf, nullptr, NN);
    gemm_kernel<128, 128, false, true><<<(NN + 63) / 64, 256, 0, stream>>>(
        cbuf, n2w2, n2b2, agg, h1, NN);

    head_kernel<<<GG, 128, 0, stream>>>(agg, h1, se, usr,
                                        h1w, h1b, h2w, h2b, h3w, h3b, h4w, h4b, h5w, h5b,
                                        (float*)d_out);
}

// Round 9
// 596.356 us; speedup vs baseline: 1.2624x; 1.2624x over previous
//
#include <hip/hip_runtime.h>

#define NN 200000
#define EE 400000
#define GG 4096

// ws layout (float offsets)
#define AGG_OFF 0
#define H1_OFF  (NN * 64)              // 12,800,000
#define SE_OFF  (H1_OFF + NN * 64)     // 25,600,000 (2*GG ints)
#define CHUNK_OFF (SE_OFF + 2 * GG)    // 25,608,192 : hidden-activation buffer (200k x 128)
// CSR + permuted-edge arrays live in the UPPER half of cbuf: only gemm n2a
// (after the last agg pass) writes past cbuf+NN*64, so they survive exactly
// as long as needed. Region budget: NN*64 floats = 51.2 MB; we use ~30.4 MB.
#define CSR_OFF (CHUNK_OFF + NN * 64)

#define NB1 ((NN + 1023) / 1024)       // 196 scan blocks

// ---------------- segment boundaries from sorted batch ----------------
__global__ void bounds_kernel(const int* __restrict__ batch, int* __restrict__ se) {
    int n = blockIdx.x * blockDim.x + threadIdx.x;
    if (n >= NN) return;
    int b = batch[n];
    if (n == 0 || batch[n - 1] != b) se[b] = n;                 // start
    if (n == NN - 1 || batch[n + 1] != b) se[GG + b] = n + 1;   // end
}

// ---------------- CSR build ----------------
__global__ void deg_kernel(const int* __restrict__ ei, int* __restrict__ cursor) {
    int e = blockIdx.x * blockDim.x + threadIdx.x;
    if (e >= EE) return;
    atomicAdd(cursor + ei[EE + e], 1);
}

// block-level exclusive scan, 1024 elements/block (256 thr x 4)
__global__ __launch_bounds__(256) void scan1_kernel(const int* __restrict__ deg,
                                                    int* __restrict__ rowptr,
                                                    int* __restrict__ partials) {
    __shared__ int sdata[256];
    int t = threadIdx.x;
    int base = blockIdx.x * 1024 + t * 4;
    int v[4]; int s = 0;
#pragma unroll
    for (int j = 0; j < 4; j++) {
        v[j] = (base + j < NN) ? deg[base + j] : 0;
        s += v[j];
    }
    sdata[t] = s;
    __syncthreads();
#pragma unroll
    for (int off = 1; off < 256; off <<= 1) {
        int x = (t >= off) ? sdata[t - off] : 0;
        __syncthreads();
        sdata[t] += x;
        __syncthreads();
    }
    int run = sdata[t] - s;   // exclusive prefix of this thread's chunk
#pragma unroll
    for (int j = 0; j < 4; j++) {
        if (base + j < NN) rowptr[base + j] = run;
        run += v[j];
    }
    if (t == 255) partials[blockIdx.x] = sdata[255];
}

__global__ __launch_bounds__(256) void scan2_kernel(int* __restrict__ partials) {
    __shared__ int sdata[256];
    int t = threadIdx.x;
    int p = (t < NB1) ? partials[t] : 0;
    sdata[t] = p;
    __syncthreads();
#pragma unroll
    for (int off = 1; off < 256; off <<= 1) {
        int x = (t >= off) ? sdata[t - off] : 0;
        __syncthreads();
        sdata[t] += x;
        __syncthreads();
    }
    if (t < NB1) partials[t] = sdata[t] - p;   // exclusive
}

__global__ __launch_bounds__(256) void scan3_kernel(int* __restrict__ rowptr,
                                                    const int* __restrict__ partials) {
    int t = threadIdx.x;
    int add = partials[blockIdx.x];
    int base = blockIdx.x * 1024 + t * 4;
#pragma unroll
    for (int j = 0; j < 4; j++)
        if (base + j < NN) rowptr[base + j] += add;
}

__global__ void scatter_kernel(const int* __restrict__ ei,
                               const int* __restrict__ rowptr,
                               int* __restrict__ cursor,
                               int* __restrict__ eidx,
                               int* __restrict__ esrc) {
    int e = blockIdx.x * blockDim.x + threadIdx.x;
    if (e >= EE) return;
    int d = ei[EE + e];
    int pos = rowptr[d] + atomicAdd(cursor + d, 1);
    eidx[pos] = e;
    esrc[pos] = ei[e];            // src id in slot order
}

// permute edge attrs into slot order: eaperm[p] = ea[eidx[p]]  (16 floats/row)
// wave per 4 slots; lane/16 selects slot, lane%16 selects element.
__global__ __launch_bounds__(256) void permute_kernel(const float* __restrict__ ea,
                                                      const int* __restrict__ eidx,
                                                      float* __restrict__ eaperm) {
    int p4 = blockIdx.x * 16 + (threadIdx.x >> 4);   // 16 slot-groups per block
    if (p4 >= EE) return;
    int elem = threadIdx.x & 15;
    int e = eidx[p4];
    eaperm[(size_t)p4 * 16 + elem] = ea[(size_t)e * 16 + elem];
}

// ---------------- gather aggregation (no atomics, short chains) ----------------
// agg[n] = xin[n] + sum_{slots p of n} relu(eaperm[p]@W + b + xin[esrc[p]])
// wave per node, lane = channel. Chain: rowptr -> esrc -> x[src]; eaperm rows
// depend only on rowptr (issue at depth 1). Inner loop unrolled x2 so two
// gathers are in flight.
__global__ __launch_bounds__(256) void agg_pass(const float* __restrict__ xin,
                                                const float* __restrict__ eaperm,
                                                const int* __restrict__ esrc,
                                                const float* __restrict__ ew,
                                                const float* __restrict__ eb,
                                                const int* __restrict__ rowptr,
                                                const int* __restrict__ cnt,
                                                float* __restrict__ agg) {
    const int lane = threadIdx.x & 63;
    int n = blockIdx.x * 4 + (threadIdx.x >> 6);
    if (n >= NN) return;   // no barriers in this kernel

    float Wr[16];
#pragma unroll
    for (int k = 0; k < 16; k++) Wr[k] = ew[k * 64 + lane];   // ew: (16,64)
    const float br = eb[lane];

    int s   = __builtin_amdgcn_readfirstlane(rowptr[n]);
    int deg = __builtin_amdgcn_readfirstlane(cnt[n]);

    float sum = xin[(size_t)n * 64 + lane];   // GINE self term (eps=0)

    for (int i = 0; i < deg; i += 2) {
        const bool two = (i + 1 < deg);
        const int p0 = s + i, p1 = s + i + 1;
        // src ids: contiguous slot loads (1 hop)
        int s0 = __builtin_amdgcn_readfirstlane(esrc[p0]);
        int s1 = two ? __builtin_amdgcn_readfirstlane(esrc[p1]) : s0;
        // edge-attr rows: addresses known immediately (depth-1 loads)
        const float4* q0 = (const float4*)(eaperm + (size_t)p0 * 16);
        const float4* q1 = (const float4*)(eaperm + (size_t)p1 * 16);
        float4 A0 = q0[0], A1 = q0[1], A2 = q0[2], A3 = q0[3];
        float4 B0, B1, B2, B3;
        if (two) { B0 = q1[0]; B1 = q1[1]; B2 = q1[2]; B3 = q1[3]; }
        // x gathers (both in flight)
        float xv0 = xin[(size_t)s0 * 64 + lane];
        float xv1 = two ? xin[(size_t)s1 * 64 + lane] : 0.0f;

        float acc0 = br;
        acc0 += A0.x * Wr[0];  acc0 += A0.y * Wr[1];
        acc0 += A0.z * Wr[2];  acc0 += A0.w * Wr[3];
        acc0 += A1.x * Wr[4];  acc0 += A1.y * Wr[5];
        acc0 += A1.z * Wr[6];  acc0 += A1.w * Wr[7];
        acc0 += A2.x * Wr[8];  acc0 += A2.y * Wr[9];
        acc0 += A2.z * Wr[10]; acc0 += A2.w * Wr[11];
        acc0 += A3.x * Wr[12]; acc0 += A3.y * Wr[13];
        acc0 += A3.z * Wr[14]; acc0 += A3.w * Wr[15];
        sum += fmaxf(acc0 + xv0, 0.0f);
        if (two) {
            float acc1 = br;
            acc1 += B0.x * Wr[0];  acc1 += B0.y * Wr[1];
            acc1 += B0.z * Wr[2];  acc1 += B0.w * Wr[3];
            acc1 += B1.x * Wr[4];  acc1 += B1.y * Wr[5];
            acc1 += B1.z * Wr[6];  acc1 += B1.w * Wr[7];
            acc1 += B2.x * Wr[8];  acc1 += B2.y * Wr[9];
            acc1 += B2.z * Wr[10]; acc1 += B2.w * Wr[11];
            acc1 += B3.x * Wr[12]; acc1 += B3.y * Wr[13];
            acc1 += B3.z * Wr[14]; acc1 += B3.w * Wr[15];
            sum += fmaxf(acc1 + xv1, 0.0f);
        }
    }
    agg[(size_t)n * 64 + lane] = sum;
}

// ---------------- tiled dense layer, W staged in LDS (K-chunked), X prefetch ----
template <int K, int C, bool RELU, bool SPLITY>
__global__ __launch_bounds__(256) void gemm_kernel(const float* __restrict__ X,
                                                   const float* __restrict__ W,
                                                   const float* __restrict__ Bv,
                                                   float* __restrict__ Ylo,
                                                   float* __restrict__ Yhi,
                                                   int rows) {
    constexpr int CPT = 8, RPT = 4;
    constexpr int COLG = C / CPT;        // 8 (C=64) or 16 (C=128)
    constexpr int ROWG = 256 / COLG;     // 32 or 16
    constexpr int BR = ROWG * RPT;       // 128 or 64 rows per block
    constexpr int KC = (K < 64) ? K : 64;  // K-chunk staged in LDS (<=32 KB)

    __shared__ float Bs[KC * C];

    const int cg = threadIdx.x % COLG;
    const int rg = threadIdx.x / COLG;
    const int c0a = cg * 4;
    const int c0b = C / 2 + cg * 4;
    const int rbase = blockIdx.x * BR + rg * RPT;

    const float* xptr[RPT];
#pragma unroll
    for (int r = 0; r < RPT; r++) {
        int rr = rbase + r;
        int ri = (rr < rows) ? rr : (rows - 1);
        xptr[r] = X + (size_t)ri * K;
    }

    float acc[RPT][CPT];
    {
        const float4* ba = (const float4*)(Bv + c0a);
        const float4* bb = (const float4*)(Bv + c0b);
        float4 v0 = ba[0], v1 = bb[0];
#pragma unroll
        for (int r = 0; r < RPT; r++) {
            acc[r][0] = v0.x; acc[r][1] = v0.y; acc[r][2] = v0.z; acc[r][3] = v0.w;
            acc[r][4] = v1.x; acc[r][5] = v1.y; acc[r][6] = v1.z; acc[r][7] = v1.w;
        }
    }

    float4 a_cur[RPT], a_nxt[RPT];
#pragma unroll
    for (int r = 0; r < RPT; r++) a_cur[r] = *(const float4*)(xptr[r]);

#pragma unroll 1
    for (int kc = 0; kc < K; kc += KC) {
        __syncthreads();
        {
            const float4* wsrc = (const float4*)(W + (size_t)kc * C);
            float4* wdst = (float4*)Bs;
            for (int i = threadIdx.x; i < KC * C / 4; i += 256) wdst[i] = wsrc[i];
        }
        __syncthreads();

#pragma unroll 2
        for (int k4 = 0; k4 < KC; k4 += 4) {
            const int knext = kc + k4 + 4;
            if (knext < K) {
#pragma unroll
                for (int r = 0; r < RPT; r++)
                    a_nxt[r] = *(const float4*)(xptr[r] + knext);
            }
#pragma unroll
            for (int kk = 0; kk < 4; kk++) {
                const float4 w0 = *(const float4*)(Bs + (k4 + kk) * C + c0a);
                const float4 w1 = *(const float4*)(Bs + (k4 + kk) * C + c0b);
#pragma unroll
                for (int r = 0; r < RPT; r++) {
                    float av = (kk == 0) ? a_cur[r].x : (kk == 1) ? a_cur[r].y
                             : (kk == 2) ? a_cur[r].z : a_cur[r].w;
                    acc[r][0] += av * w0.x; acc[r][1] += av * w0.y;
                    acc[r][2] += av * w0.z; acc[r][3] += av * w0.w;
                    acc[r][4] += av * w1.x; acc[r][5] += av * w1.y;
                    acc[r][6] += av * w1.z; acc[r][7] += av * w1.w;
                }
            }
#pragma unroll
            for (int r = 0; r < RPT; r++) a_cur[r] = a_nxt[r];
        }
    }

#pragma unroll
    for (int r = 0; r < RPT; r++) {
        int rr = rbase + r;
        if (rr < rows) {
            float4 v0, v1;
            v0.x = RELU ? fmaxf(acc[r][0], 0.0f) : acc[r][0];
            v0.y = RELU ? fmaxf(acc[r][1], 0.0f) : acc[r][1];
            v0.z = RELU ? fmaxf(acc[r][2], 0.0f) : acc[r][2];
            v0.w = RELU ? fmaxf(acc[r][3], 0.0f) : acc[r][3];
            v1.x = RELU ? fmaxf(acc[r][4], 0.0f) : acc[r][4];
            v1.y = RELU ? fmaxf(acc[r][5], 0.0f) : acc[r][5];
            v1.z = RELU ? fmaxf(acc[r][6], 0.0f) : acc[r][6];
            v1.w = RELU ? fmaxf(acc[r][7], 0.0f) : acc[r][7];
            if (SPLITY) {
                *(float4*)(Ylo + (size_t)rr * 64 + c0a) = v0;
                *(float4*)(Yhi + (size_t)rr * 64 + (c0b - C / 2)) = v1;
            } else {
                *(float4*)(Ylo + (size_t)rr * C + c0a) = v0;
                *(float4*)(Ylo + (size_t)rr * C + c0b) = v1;
            }
        }
    }
}

// ---------------- head: mean-pool (via segment bounds) + 5-layer MLP ----------------
__global__ __launch_bounds__(128) void head_kernel(const float* __restrict__ hlo,
                                                   const float* __restrict__ hhi,
                                                   const int* __restrict__ se,
                                                   const float* __restrict__ usr,
                                                   const float* __restrict__ h1w, const float* __restrict__ h1b,
                                                   const float* __restrict__ h2w, const float* __restrict__ h2b,
                                                   const float* __restrict__ h3w, const float* __restrict__ h3b,
                                                   const float* __restrict__ h4w, const float* __restrict__ h4b,
                                                   const float* __restrict__ h5w, const float* __restrict__ h5b,
                                                   float* __restrict__ out) {
    int g = blockIdx.x;
    int c = threadIdx.x;
    __shared__ float z0[140];
    __shared__ float z1[128];
    __shared__ float z2[64];
    __shared__ float z3[32];
    __shared__ float z4[16];

    int s = se[g], e = se[GG + g];
    float sum = 0.0f;
    if (c < 64) {
        for (int n = s; n < e; n++) sum += hlo[(size_t)n * 64 + c];
    } else {
        for (int n = s; n < e; n++) sum += hhi[(size_t)n * 64 + (c - 64)];
    }
    float cnt = fmaxf((float)(e - s), 1.0f);
    z0[c] = sum / cnt;
    if (c < 12) z0[128 + c] = usr[g * 12 + c];
    __syncthreads();

    {
        float acc = h1b[c];
        for (int k = 0; k < 140; k++) acc += z0[k] * h1w[k * 128 + c];
        z1[c] = fmaxf(acc, 0.0f);
    }
    __syncthreads();
    if (c < 64) {
        float acc = h2b[c];
        for (int k = 0; k < 128; k++) acc += z1[k] * h2w[k * 64 + c];
        z2[c] = fmaxf(acc, 0.0f);
    }
    __syncthreads();
    if (c < 32) {
        float acc = h3b[c];
        for (int k = 0; k < 64; k++) acc += z2[k] * h3w[k * 32 + c];
        z3[c] = fmaxf(acc, 0.0f);
    }
    __syncthreads();
    if (c < 16) {
        float acc = h4b[c];
        for (int k = 0; k < 32; k++) acc += z3[k] * h4w[k * 16 + c];
        z4[c] = fmaxf(acc, 0.0f);
    }
    __syncthreads();
    if (c == 0) {
        float acc = h5b[0];
        for (int k = 0; k < 16; k++) acc += z4[k] * h5w[k];
        out[g] = acc;
    }
}

extern "C" void kernel_launch(void* const* d_in, const int* in_sizes, int n_in,
                              void* d_out, int out_size, void* d_ws, size_t ws_size,
                              hipStream_t stream) {
    const float* x    = (const float*)d_in[0];
    const int*   ei   = (const int*)d_in[1];
    const float* ea   = (const float*)d_in[2];
    const int*   batch= (const int*)d_in[3];
    const float* usr  = (const float*)d_in[4];
    const float* e1w  = (const float*)d_in[5],  *e1b  = (const float*)d_in[6];
    const float* n1w1 = (const float*)d_in[7],  *n1b1 = (const float*)d_in[8];
    const float* n1w2 = (const float*)d_in[9],  *n1b2 = (const float*)d_in[10];
    const float* e2w  = (const float*)d_in[11], *e2b  = (const float*)d_in[12];
    const float* n2w1 = (const float*)d_in[13], *n2b1 = (const float*)d_in[14];
    const float* n2w2 = (const float*)d_in[15], *n2b2 = (const float*)d_in[16];
    const float* h1w  = (const float*)d_in[17], *h1b  = (const float*)d_in[18];
    const float* h2w  = (const float*)d_in[19], *h2b  = (const float*)d_in[20];
    const float* h3w  = (const float*)d_in[21], *h3b  = (const float*)d_in[22];
    const float* h4w  = (const float*)d_in[23], *h4b  = (const float*)d_in[24];
    const float* h5w  = (const float*)d_in[25], *h5b  = (const float*)d_in[26];

    float* w    = (float*)d_ws;
    float* agg  = w + AGG_OFF;
    float* h1   = w + H1_OFF;
    int*   se   = (int*)(w + SE_OFF);
    float* cbuf = w + CHUNK_OFF;

    int*   rowptr   = (int*)(w + CSR_OFF);
    int*   cursor   = rowptr + NN;
    int*   eidx     = cursor + NN;
    int*   esrc     = eidx + EE;
    int*   partials = esrc + EE;
    float* eaperm   = (float*)(partials + 256);

    hipMemsetAsync(se, 0, (size_t)GG * 2 * sizeof(int), stream);
    hipMemsetAsync(cursor, 0, (size_t)NN * sizeof(int), stream);

    bounds_kernel<<<(NN + 255) / 256, 256, 0, stream>>>(batch, se);

    // ---- CSR build + slot-order edge materialization (shared by both layers) ----
    deg_kernel<<<(EE + 255) / 256, 256, 0, stream>>>(ei, cursor);
    scan1_kernel<<<NB1, 256, 0, stream>>>(cursor, rowptr, partials);
    scan2_kernel<<<1, 256, 0, stream>>>(partials);
    scan3_kernel<<<NB1, 256, 0, stream>>>(rowptr, partials);
    hipMemsetAsync(cursor, 0, (size_t)NN * sizeof(int), stream);
    scatter_kernel<<<(EE + 255) / 256, 256, 0, stream>>>(ei, rowptr, cursor, eidx, esrc);
    // after scatter, cursor[n] == deg[n]
    permute_kernel<<<(EE + 15) / 16, 256, 0, stream>>>(ea, eidx, eaperm);

    // ---- layer 1 ----
    agg_pass<<<(NN + 3) / 4, 256, 0, stream>>>(x, eaperm, esrc, e1w, e1b, rowptr, cursor, agg);
    gemm_kernel<64, 64, true, false><<<(NN + 127) / 128, 256, 0, stream>>>(
        agg, n1w1, n1b1, cbuf, nullptr, NN);
    gemm_kernel<64, 64, true, false><<<(NN + 127) / 128, 256, 0, stream>>>(
        cbuf, n1w2, n1b2, h1, nullptr, NN);

    // ---- layer 2 ---- (CSR intact: n1a only wrote cbuf[0:NN*64])
    agg_pass<<<(NN + 3) / 4, 256, 0, stream>>>(h1, eaperm, esrc, e2w, e2b, rowptr, cursor, agg);
    gemm_kernel<64, 128, true, false><<<(NN + 63) / 64, 256, 0, stream>>>(
        agg, n2w1, n2b1, cbuf, nullptr, NN);
    gemm_kernel<128, 128, false, true><<<(NN + 63) / 64, 256, 0, stream>>>(
        cbuf, n2w2, n2b2, agg, h1, NN);

    head_kernel<<<GG, 128, 0, stream>>>(agg, h1, se, usr,
                                        h1w, h1b, h2w, h2b, h3w, h3b, h4w, h4b, h5w, h5b,
                                        (float*)d_out);
}

// Round 10
// 521.672 us; speedup vs baseline: 1.4431x; 1.1432x over previous
//
#include <hip/hip_runtime.h>

#define NN 200000
#define EE 400000
#define GG 4096

// ws layout (float offsets)
#define AGG_OFF 0
#define H1_OFF  (NN * 64)              // 12,800,000
#define SE_OFF  (H1_OFF + NN * 64)     // 25,600,000 (2*GG ints)
#define CHUNK_OFF (SE_OFF + 2 * GG)    // 25,608,192 : H2 buffer (200k x 128)
// CSR + permuted-edge arrays live at CHUNK_OFF + NN*64: the only kernel that
// writes past cbuf+NN*64 is gemm n2a, which runs after the last agg_pass, so
// the CSR data is dead by then. head reads only cbuf (written by n2a).
#define CSR_OFF (CHUNK_OFF + NN * 64)

#define NB1 ((NN + 1023) / 1024)       // 196 scan blocks

// ---------------- segment boundaries from sorted batch ----------------
__global__ void bounds_kernel(const int* __restrict__ batch, int* __restrict__ se) {
    int n = blockIdx.x * blockDim.x + threadIdx.x;
    if (n >= NN) return;
    int b = batch[n];
    if (n == 0 || batch[n - 1] != b) se[b] = n;                 // start
    if (n == NN - 1 || batch[n + 1] != b) se[GG + b] = n + 1;   // end
}

// ---------------- CSR build ----------------
__global__ void deg_kernel(const int* __restrict__ ei, int* __restrict__ cursor) {
    int e = blockIdx.x * blockDim.x + threadIdx.x;
    if (e >= EE) return;
    atomicAdd(cursor + ei[EE + e], 1);
}

__global__ __launch_bounds__(256) void scan1_kernel(const int* __restrict__ deg,
                                                    int* __restrict__ rowptr,
                                                    int* __restrict__ partials) {
    __shared__ int sdata[256];
    int t = threadIdx.x;
    int base = blockIdx.x * 1024 + t * 4;
    int v[4]; int s = 0;
#pragma unroll
    for (int j = 0; j < 4; j++) {
        v[j] = (base + j < NN) ? deg[base + j] : 0;
        s += v[j];
    }
    sdata[t] = s;
    __syncthreads();
#pragma unroll
    for (int off = 1; off < 256; off <<= 1) {
        int x = (t >= off) ? sdata[t - off] : 0;
        __syncthreads();
        sdata[t] += x;
        __syncthreads();
    }
    int run = sdata[t] - s;
#pragma unroll
    for (int j = 0; j < 4; j++) {
        if (base + j < NN) rowptr[base + j] = run;
        run += v[j];
    }
    if (t == 255) partials[blockIdx.x] = sdata[255];
}

__global__ __launch_bounds__(256) void scan2_kernel(int* __restrict__ partials) {
    __shared__ int sdata[256];
    int t = threadIdx.x;
    int p = (t < NB1) ? partials[t] : 0;
    sdata[t] = p;
    __syncthreads();
#pragma unroll
    for (int off = 1; off < 256; off <<= 1) {
        int x = (t >= off) ? sdata[t - off] : 0;
        __syncthreads();
        sdata[t] += x;
        __syncthreads();
    }
    if (t < NB1) partials[t] = sdata[t] - p;
}

__global__ __launch_bounds__(256) void scan3_kernel(int* __restrict__ rowptr,
                                                    const int* __restrict__ partials) {
    int t = threadIdx.x;
    int add = partials[blockIdx.x];
    int base = blockIdx.x * 1024 + t * 4;
#pragma unroll
    for (int j = 0; j < 4; j++)
        if (base + j < NN) rowptr[base + j] += add;
}

__global__ void scatter_kernel(const int* __restrict__ ei,
                               const int* __restrict__ rowptr,
                               int* __restrict__ cursor,
                               int* __restrict__ eidx,
                               int* __restrict__ esrc) {
    int e = blockIdx.x * blockDim.x + threadIdx.x;
    if (e >= EE) return;
    int d = ei[EE + e];
    int pos = rowptr[d] + atomicAdd(cursor + d, 1);
    eidx[pos] = e;
    esrc[pos] = ei[e];
}

// permute edge attrs into slot order: eaperm[p] = ea[eidx[p]]
__global__ __launch_bounds__(256) void permute_kernel(const float* __restrict__ ea,
                                                      const int* __restrict__ eidx,
                                                      float* __restrict__ eaperm) {
    int p4 = blockIdx.x * 16 + (threadIdx.x >> 4);
    if (p4 >= EE) return;
    int elem = threadIdx.x & 15;
    int e = eidx[p4];
    eaperm[(size_t)p4 * 16 + elem] = ea[(size_t)e * 16 + elem];
}

// ---------------- gather aggregation (no atomics, short chains) ----------------
__global__ __launch_bounds__(256) void agg_pass(const float* __restrict__ xin,
                                                const float* __restrict__ eaperm,
                                                const int* __restrict__ esrc,
                                                const float* __restrict__ ew,
                                                const float* __restrict__ eb,
                                                const int* __restrict__ rowptr,
                                                const int* __restrict__ cnt,
                                                float* __restrict__ agg) {
    const int lane = threadIdx.x & 63;
    int n = blockIdx.x * 4 + (threadIdx.x >> 6);
    if (n >= NN) return;

    float Wr[16];
#pragma unroll
    for (int k = 0; k < 16; k++) Wr[k] = ew[k * 64 + lane];
    const float br = eb[lane];

    int s   = __builtin_amdgcn_readfirstlane(rowptr[n]);
    int deg = __builtin_amdgcn_readfirstlane(cnt[n]);

    float sum = xin[(size_t)n * 64 + lane];

    for (int i = 0; i < deg; i += 2) {
        const bool two = (i + 1 < deg);
        const int p0 = s + i, p1 = s + i + 1;
        int s0 = __builtin_amdgcn_readfirstlane(esrc[p0]);
        int s1 = two ? __builtin_amdgcn_readfirstlane(esrc[p1]) : s0;
        const float4* q0 = (const float4*)(eaperm + (size_t)p0 * 16);
        const float4* q1 = (const float4*)(eaperm + (size_t)p1 * 16);
        float4 A0 = q0[0], A1 = q0[1], A2 = q0[2], A3 = q0[3];
        float4 B0, B1, B2, B3;
        if (two) { B0 = q1[0]; B1 = q1[1]; B2 = q1[2]; B3 = q1[3]; }
        float xv0 = xin[(size_t)s0 * 64 + lane];
        float xv1 = two ? xin[(size_t)s1 * 64 + lane] : 0.0f;

        float acc0 = br;
        acc0 += A0.x * Wr[0];  acc0 += A0.y * Wr[1];
        acc0 += A0.z * Wr[2];  acc0 += A0.w * Wr[3];
        acc0 += A1.x * Wr[4];  acc0 += A1.y * Wr[5];
        acc0 += A1.z * Wr[6];  acc0 += A1.w * Wr[7];
        acc0 += A2.x * Wr[8];  acc0 += A2.y * Wr[9];
        acc0 += A2.z * Wr[10]; acc0 += A2.w * Wr[11];
        acc0 += A3.x * Wr[12]; acc0 += A3.y * Wr[13];
        acc0 += A3.z * Wr[14]; acc0 += A3.w * Wr[15];
        sum += fmaxf(acc0 + xv0, 0.0f);
        if (two) {
            float acc1 = br;
            acc1 += B0.x * Wr[0];  acc1 += B0.y * Wr[1];
            acc1 += B0.z * Wr[2];  acc1 += B0.w * Wr[3];
            acc1 += B1.x * Wr[4];  acc1 += B1.y * Wr[5];
            acc1 += B1.z * Wr[6];  acc1 += B1.w * Wr[7];
            acc1 += B2.x * Wr[8];  acc1 += B2.y * Wr[9];
            acc1 += B2.z * Wr[10]; acc1 += B2.w * Wr[11];
            acc1 += B3.x * Wr[12]; acc1 += B3.y * Wr[13];
            acc1 += B3.z * Wr[14]; acc1 += B3.w * Wr[15];
            sum += fmaxf(acc1 + xv1, 0.0f);
        }
    }
    agg[(size_t)n * 64 + lane] = sum;
}

// ---------------- fused node-1 MLP: Y = relu( relu(X@W1+b1) @ W2 + b2 ) ------
// 64 rows/block; W1,W2 (16 KB each) + Htmp tile (stride-68 pad, 17 KB) in LDS.
// Thread tile 2 rows x 8 cols, cols split {cg*4, 32+cg*4} (<=2-way banks).
__global__ __launch_bounds__(256) void node1_fused(const float* __restrict__ X,
                                                   const float* __restrict__ W1,
                                                   const float* __restrict__ B1,
                                                   const float* __restrict__ W2,
                                                   const float* __restrict__ B2,
                                                   float* __restrict__ Y,
                                                   int rows) {
    __shared__ float W1s[64 * 64];
    __shared__ float W2s[64 * 64];
    __shared__ float Hs[64 * 68];         // padded leading dim

    {
        const float4* s1 = (const float4*)W1;
        const float4* s2 = (const float4*)W2;
        float4* d1 = (float4*)W1s;
        float4* d2 = (float4*)W2s;
        for (int i = threadIdx.x; i < 1024; i += 256) { d1[i] = s1[i]; d2[i] = s2[i]; }
    }

    const int cg = threadIdx.x % 8;
    const int rg = threadIdx.x / 8;       // 0..31
    const int c0a = cg * 4, c0b = 32 + cg * 4;
    const int rbase = blockIdx.x * 64 + rg * 2;

    const float* xptr[2];
#pragma unroll
    for (int r = 0; r < 2; r++) {
        int rr = rbase + r;
        int ri = (rr < rows) ? rr : (rows - 1);
        xptr[r] = X + (size_t)ri * 64;
    }

    float acc[2][8];
    {
        const float4 v0 = *(const float4*)(B1 + c0a);
        const float4 v1 = *(const float4*)(B1 + c0b);
#pragma unroll
        for (int r = 0; r < 2; r++) {
            acc[r][0] = v0.x; acc[r][1] = v0.y; acc[r][2] = v0.z; acc[r][3] = v0.w;
            acc[r][4] = v1.x; acc[r][5] = v1.y; acc[r][6] = v1.z; acc[r][7] = v1.w;
        }
    }

    float4 a_cur[2], a_nxt[2];
#pragma unroll
    for (int r = 0; r < 2; r++) a_cur[r] = *(const float4*)(xptr[r]);

    __syncthreads();   // W1s/W2s staged

    // ---- GEMM1: Htmp = relu(X@W1 + b1) -> Hs ----
#pragma unroll 2
    for (int k4 = 0; k4 < 64; k4 += 4) {
        if (k4 + 4 < 64) {
#pragma unroll
            for (int r = 0; r < 2; r++) a_nxt[r] = *(const float4*)(xptr[r] + k4 + 4);
        }
#pragma unroll
        for (int kk = 0; kk < 4; kk++) {
            const float4 w0 = *(const float4*)(W1s + (k4 + kk) * 64 + c0a);
            const float4 w1 = *(const float4*)(W1s + (k4 + kk) * 64 + c0b);
#pragma unroll
            for (int r = 0; r < 2; r++) {
                float av = (kk == 0) ? a_cur[r].x : (kk == 1) ? a_cur[r].y
                         : (kk == 2) ? a_cur[r].z : a_cur[r].w;
                acc[r][0] += av * w0.x; acc[r][1] += av * w0.y;
                acc[r][2] += av * w0.z; acc[r][3] += av * w0.w;
                acc[r][4] += av * w1.x; acc[r][5] += av * w1.y;
                acc[r][6] += av * w1.z; acc[r][7] += av * w1.w;
            }
        }
#pragma unroll
        for (int r = 0; r < 2; r++) a_cur[r] = a_nxt[r];
    }

#pragma unroll
    for (int r = 0; r < 2; r++) {
        const int lrow = rg * 2 + r;
        float4 v0, v1;
        v0.x = fmaxf(acc[r][0], 0.0f); v0.y = fmaxf(acc[r][1], 0.0f);
        v0.z = fmaxf(acc[r][2], 0.0f); v0.w = fmaxf(acc[r][3], 0.0f);
        v1.x = fmaxf(acc[r][4], 0.0f); v1.y = fmaxf(acc[r][5], 0.0f);
        v1.z = fmaxf(acc[r][6], 0.0f); v1.w = fmaxf(acc[r][7], 0.0f);
        *(float4*)(Hs + lrow * 68 + c0a) = v0;
        *(float4*)(Hs + lrow * 68 + c0b) = v1;
    }

    // ---- GEMM2: Y = relu(Htmp@W2 + b2) ----
    {
        const float4 v0 = *(const float4*)(B2 + c0a);
        const float4 v1 = *(const float4*)(B2 + c0b);
#pragma unroll
        for (int r = 0; r < 2; r++) {
            acc[r][0] = v0.x; acc[r][1] = v0.y; acc[r][2] = v0.z; acc[r][3] = v0.w;
            acc[r][4] = v1.x; acc[r][5] = v1.y; acc[r][6] = v1.z; acc[r][7] = v1.w;
        }
    }
    __syncthreads();   // Hs fully written

#pragma unroll 2
    for (int k4 = 0; k4 < 64; k4 += 4) {
        float4 a[2];
#pragma unroll
        for (int r = 0; r < 2; r++) a[r] = *(const float4*)(Hs + (rg * 2 + r) * 68 + k4);
#pragma unroll
        for (int kk = 0; kk < 4; kk++) {
            const float4 w0 = *(const float4*)(W2s + (k4 + kk) * 64 + c0a);
            const float4 w1 = *(const float4*)(W2s + (k4 + kk) * 64 + c0b);
#pragma unroll
            for (int r = 0; r < 2; r++) {
                float av = (kk == 0) ? a[r].x : (kk == 1) ? a[r].y
                         : (kk == 2) ? a[r].z : a[r].w;
                acc[r][0] += av * w0.x; acc[r][1] += av * w0.y;
                acc[r][2] += av * w0.z; acc[r][3] += av * w0.w;
                acc[r][4] += av * w1.x; acc[r][5] += av * w1.y;
                acc[r][6] += av * w1.z; acc[r][7] += av * w1.w;
            }
        }
    }

#pragma unroll
    for (int r = 0; r < 2; r++) {
        int rr = rbase + r;
        if (rr < rows) {
            float4 v0, v1;
            v0.x = fmaxf(acc[r][0], 0.0f); v0.y = fmaxf(acc[r][1], 0.0f);
            v0.z = fmaxf(acc[r][2], 0.0f); v0.w = fmaxf(acc[r][3], 0.0f);
            v1.x = fmaxf(acc[r][4], 0.0f); v1.y = fmaxf(acc[r][5], 0.0f);
            v1.z = fmaxf(acc[r][6], 0.0f); v1.w = fmaxf(acc[r][7], 0.0f);
            *(float4*)(Y + (size_t)rr * 64 + c0a) = v0;
            *(float4*)(Y + (size_t)rr * 64 + c0b) = v1;
        }
    }
}

// ---------------- tiled dense layer, W staged in LDS (used for n2a) ----------
template <int K, int C, bool RELU>
__global__ __launch_bounds__(256) void gemm_kernel(const float* __restrict__ X,
                                                   const float* __restrict__ W,
                                                   const float* __restrict__ Bv,
                                                   float* __restrict__ Y,
                                                   int rows) {
    constexpr int CPT = 8, RPT = 4;
    constexpr int COLG = C / CPT;
    constexpr int ROWG = 256 / COLG;
    constexpr int BR = ROWG * RPT;
    constexpr int KC = (K < 64) ? K : 64;

    __shared__ float Bs[KC * C];

    const int cg = threadIdx.x % COLG;
    const int rg = threadIdx.x / COLG;
    const int c0a = cg * 4;
    const int c0b = C / 2 + cg * 4;
    const int rbase = blockIdx.x * BR + rg * RPT;

    const float* xptr[RPT];
#pragma unroll
    for (int r = 0; r < RPT; r++) {
        int rr = rbase + r;
        int ri = (rr < rows) ? rr : (rows - 1);
        xptr[r] = X + (size_t)ri * K;
    }

    float acc[RPT][CPT];
    {
        const float4* ba = (const float4*)(Bv + c0a);
        const float4* bb = (const float4*)(Bv + c0b);
        float4 v0 = ba[0], v1 = bb[0];
#pragma unroll
        for (int r = 0; r < RPT; r++) {
            acc[r][0] = v0.x; acc[r][1] = v0.y; acc[r][2] = v0.z; acc[r][3] = v0.w;
            acc[r][4] = v1.x; acc[r][5] = v1.y; acc[r][6] = v1.z; acc[r][7] = v1.w;
        }
    }

    float4 a_cur[RPT], a_nxt[RPT];
#pragma unroll
    for (int r = 0; r < RPT; r++) a_cur[r] = *(const float4*)(xptr[r]);

#pragma unroll 1
    for (int kc = 0; kc < K; kc += KC) {
        __syncthreads();
        {
            const float4* wsrc = (const float4*)(W + (size_t)kc * C);
            float4* wdst = (float4*)Bs;
            for (int i = threadIdx.x; i < KC * C / 4; i += 256) wdst[i] = wsrc[i];
        }
        __syncthreads();

#pragma unroll 2
        for (int k4 = 0; k4 < KC; k4 += 4) {
            const int knext = kc + k4 + 4;
            if (knext < K) {
#pragma unroll
                for (int r = 0; r < RPT; r++)
                    a_nxt[r] = *(const float4*)(xptr[r] + knext);
            }
#pragma unroll
            for (int kk = 0; kk < 4; kk++) {
                const float4 w0 = *(const float4*)(Bs + (k4 + kk) * C + c0a);
                const float4 w1 = *(const float4*)(Bs + (k4 + kk) * C + c0b);
#pragma unroll
                for (int r = 0; r < RPT; r++) {
                    float av = (kk == 0) ? a_cur[r].x : (kk == 1) ? a_cur[r].y
                             : (kk == 2) ? a_cur[r].z : a_cur[r].w;
                    acc[r][0] += av * w0.x; acc[r][1] += av * w0.y;
                    acc[r][2] += av * w0.z; acc[r][3] += av * w0.w;
                    acc[r][4] += av * w1.x; acc[r][5] += av * w1.y;
                    acc[r][6] += av * w1.z; acc[r][7] += av * w1.w;
                }
            }
#pragma unroll
            for (int r = 0; r < RPT; r++) a_cur[r] = a_nxt[r];
        }
    }

#pragma unroll
    for (int r = 0; r < RPT; r++) {
        int rr = rbase + r;
        if (rr < rows) {
            float4 v0, v1;
            v0.x = RELU ? fmaxf(acc[r][0], 0.0f) : acc[r][0];
            v0.y = RELU ? fmaxf(acc[r][1], 0.0f) : acc[r][1];
            v0.z = RELU ? fmaxf(acc[r][2], 0.0f) : acc[r][2];
            v0.w = RELU ? fmaxf(acc[r][3], 0.0f) : acc[r][3];
            v1.x = RELU ? fmaxf(acc[r][4], 0.0f) : acc[r][4];
            v1.y = RELU ? fmaxf(acc[r][5], 0.0f) : acc[r][5];
            v1.z = RELU ? fmaxf(acc[r][6], 0.0f) : acc[r][6];
            v1.w = RELU ? fmaxf(acc[r][7], 0.0f) : acc[r][7];
            *(float4*)(Y + (size_t)rr * C + c0a) = v0;
            *(float4*)(Y + (size_t)rr * C + c0b) = v1;
        }
    }
}

// ---------------- head: mean-pool H2, emb = m@W2+b2 (pool/W2 commuted), MLP ----
__global__ __launch_bounds__(128) void head_kernel(const float* __restrict__ H2,  // [NN x 128]
                                                   const int* __restrict__ se,
                                                   const float* __restrict__ usr,
                                                   const float* __restrict__ w2, const float* __restrict__ b2,
                                                   const float* __restrict__ h1w, const float* __restrict__ h1b,
                                                   const float* __restrict__ h2w, const float* __restrict__ h2b,
                                                   const float* __restrict__ h3w, const float* __restrict__ h3b,
                                                   const float* __restrict__ h4w, const float* __restrict__ h4b,
                                                   const float* __restrict__ h5w, const float* __restrict__ h5b,
                                                   float* __restrict__ out) {
    int g = blockIdx.x;
    int c = threadIdx.x;
    __shared__ float m[128];
    __shared__ float z0[140];
    __shared__ float z1[128];
    __shared__ float z2[64];
    __shared__ float z3[32];
    __shared__ float z4[16];

    int s = se[g], e = se[GG + g];
    float sum = 0.0f;
    for (int n = s; n < e; n++) sum += H2[(size_t)n * 128 + c];
    float cnt = fmaxf((float)(e - s), 1.0f);
    m[c] = sum / cnt;
    __syncthreads();

    // emb = mean(H2) @ n2w2 + n2b2  (exact: pooling commutes with linear map;
    // empty graph -> emb = 0 to match reference semantics)
    {
        float acc = b2[c];
        for (int k = 0; k < 128; k++) acc += m[k] * w2[k * 128 + c];
        z0[c] = (e > s) ? acc : 0.0f;
    }
    if (c < 12) z0[128 + c] = usr[g * 12 + c];
    __syncthreads();

    {
        float acc = h1b[c];
        for (int k = 0; k < 140; k++) acc += z0[k] * h1w[k * 128 + c];
        z1[c] = fmaxf(acc, 0.0f);
    }
    __syncthreads();
    if (c < 64) {
        float acc = h2b[c];
        for (int k = 0; k < 128; k++) acc += z1[k] * h2w[k * 64 + c];
        z2[c] = fmaxf(acc, 0.0f);
    }
    __syncthreads();
    if (c < 32) {
        float acc = h3b[c];
        for (int k = 0; k < 64; k++) acc += z2[k] * h3w[k * 32 + c];
        z3[c] = fmaxf(acc, 0.0f);
    }
    __syncthreads();
    if (c < 16) {
        float acc = h4b[c];
        for (int k = 0; k < 32; k++) acc += z3[k] * h4w[k * 16 + c];
        z4[c] = fmaxf(acc, 0.0f);
    }
    __syncthreads();
    if (c == 0) {
        float acc = h5b[0];
        for (int k = 0; k < 16; k++) acc += z4[k] * h5w[k];
        out[g] = acc;
    }
}

extern "C" void kernel_launch(void* const* d_in, const int* in_sizes, int n_in,
                              void* d_out, int out_size, void* d_ws, size_t ws_size,
                              hipStream_t stream) {
    const float* x    = (const float*)d_in[0];
    const int*   ei   = (const int*)d_in[1];
    const float* ea   = (const float*)d_in[2];
    const int*   batch= (const int*)d_in[3];
    const float* usr  = (const float*)d_in[4];
    const float* e1w  = (const float*)d_in[5],  *e1b  = (const float*)d_in[6];
    const float* n1w1 = (const float*)d_in[7],  *n1b1 = (const float*)d_in[8];
    const float* n1w2 = (const float*)d_in[9],  *n1b2 = (const float*)d_in[10];
    const float* e2w  = (const float*)d_in[11], *e2b  = (const float*)d_in[12];
    const float* n2w1 = (const float*)d_in[13], *n2b1 = (const float*)d_in[14];
    const float* n2w2 = (const float*)d_in[15], *n2b2 = (const float*)d_in[16];
    const float* h1w  = (const float*)d_in[17], *h1b  = (const float*)d_in[18];
    const float* h2w  = (const float*)d_in[19], *h2b  = (const float*)d_in[20];
    const float* h3w  = (const float*)d_in[21], *h3b  = (const float*)d_in[22];
    const float* h4w  = (const float*)d_in[23], *h4b  = (const float*)d_in[24];
    const float* h5w  = (const float*)d_in[25], *h5b  = (const float*)d_in[26];

    float* w    = (float*)d_ws;
    float* agg  = w + AGG_OFF;
    float* h1   = w + H1_OFF;
    int*   se   = (int*)(w + SE_OFF);
    float* cbuf = w + CHUNK_OFF;

    int*   rowptr   = (int*)(w + CSR_OFF);
    int*   cursor   = rowptr + NN;
    int*   eidx     = cursor + NN;
    int*   esrc     = eidx + EE;
    int*   partials = esrc + EE;
    float* eaperm   = (float*)(partials + 256);

    hipMemsetAsync(se, 0, (size_t)GG * 2 * sizeof(int), stream);
    hipMemsetAsync(cursor, 0, (size_t)NN * sizeof(int), stream);

    bounds_kernel<<<(NN + 255) / 256, 256, 0, stream>>>(batch, se);

    // ---- CSR build + slot-order edge materialization (shared by both layers) ----
    deg_kernel<<<(EE + 255) / 256, 256, 0, stream>>>(ei, cursor);
    scan1_kernel<<<NB1, 256, 0, stream>>>(cursor, rowptr, partials);
    scan2_kernel<<<1, 256, 0, stream>>>(partials);
    scan3_kernel<<<NB1, 256, 0, stream>>>(rowptr, partials);
    hipMemsetAsync(cursor, 0, (size_t)NN * sizeof(int), stream);
    scatter_kernel<<<(EE + 255) / 256, 256, 0, stream>>>(ei, rowptr, cursor, eidx, esrc);
    permute_kernel<<<(EE + 15) / 16, 256, 0, stream>>>(ea, eidx, eaperm);

    // ---- layer 1 ----
    agg_pass<<<(NN + 3) / 4, 256, 0, stream>>>(x, eaperm, esrc, e1w, e1b, rowptr, cursor, agg);
    node1_fused<<<(NN + 63) / 64, 256, 0, stream>>>(agg, n1w1, n1b1, n1w2, n1b2, h1, NN);

    // ---- layer 2 ---- (CSR intact until after this agg_pass)
    agg_pass<<<(NN + 3) / 4, 256, 0, stream>>>(h1, eaperm, esrc, e2w, e2b, rowptr, cursor, agg);
    // H2 = relu(agg @ n2w1 + n2b1)  [NN x 128] -> cbuf (clobbers dead CSR region)
    gemm_kernel<64, 128, true><<<(NN + 63) / 64, 256, 0, stream>>>(
        agg, n2w1, n2b1, cbuf, NN);

    // ---- head: pool(H2) then n2w2 (commuted) + 5-layer MLP ----
    head_kernel<<<GG, 128, 0, stream>>>(cbuf, se, usr, n2w2, n2b2,
                                        h1w, h1b, h2w, h2b, h3w, h3b, h4w, h4b, h5w, h5b,
                                        (float*)d_out);
}

// Round 11
// 504.096 us; speedup vs baseline: 1.4935x; 1.0349x over previous
//
#include <hip/hip_runtime.h>

#define NN 200000
#define EE 400000
#define GG 4096

// ws layout (float offsets)
#define AGG_OFF 0
#define H1_OFF  (NN * 64)                  // 12,800,000
#define SE_OFF  (H1_OFF + NN * 64)         // 25,600,000 (2*GG ints)
#define GSUM_OFF (SE_OFF + 2 * GG)         // 25,608,192 (GG*128 floats, per-graph H2 sums)
#define CSR_OFF (GSUM_OFF + GG * 128)      // CSR + permuted edges (~30.4 MB); never clobbered

#define NB1 ((NN + 1023) / 1024)           // 196 scan blocks

// ---------------- segment boundaries from sorted batch ----------------
__global__ void bounds_kernel(const int* __restrict__ batch, int* __restrict__ se) {
    int n = blockIdx.x * blockDim.x + threadIdx.x;
    if (n >= NN) return;
    int b = batch[n];
    if (n == 0 || batch[n - 1] != b) se[b] = n;                 // start
    if (n == NN - 1 || batch[n + 1] != b) se[GG + b] = n + 1;   // end
}

// ---------------- CSR build ----------------
__global__ void deg_kernel(const int* __restrict__ ei, int* __restrict__ cursor) {
    int e = blockIdx.x * blockDim.x + threadIdx.x;
    if (e >= EE) return;
    atomicAdd(cursor + ei[EE + e], 1);
}

__global__ __launch_bounds__(256) void scan1_kernel(const int* __restrict__ deg,
                                                    int* __restrict__ rowptr,
                                                    int* __restrict__ partials) {
    __shared__ int sdata[256];
    int t = threadIdx.x;
    int base = blockIdx.x * 1024 + t * 4;
    int v[4]; int s = 0;
#pragma unroll
    for (int j = 0; j < 4; j++) {
        v[j] = (base + j < NN) ? deg[base + j] : 0;
        s += v[j];
    }
    sdata[t] = s;
    __syncthreads();
#pragma unroll
    for (int off = 1; off < 256; off <<= 1) {
        int x = (t >= off) ? sdata[t - off] : 0;
        __syncthreads();
        sdata[t] += x;
        __syncthreads();
    }
    int run = sdata[t] - s;
#pragma unroll
    for (int j = 0; j < 4; j++) {
        if (base + j < NN) rowptr[base + j] = run;
        run += v[j];
    }
    if (t == 255) partials[blockIdx.x] = sdata[255];
}

__global__ __launch_bounds__(256) void scan2_kernel(int* __restrict__ partials) {
    __shared__ int sdata[256];
    int t = threadIdx.x;
    int p = (t < NB1) ? partials[t] : 0;
    sdata[t] = p;
    __syncthreads();
#pragma unroll
    for (int off = 1; off < 256; off <<= 1) {
        int x = (t >= off) ? sdata[t - off] : 0;
        __syncthreads();
        sdata[t] += x;
        __syncthreads();
    }
    if (t < NB1) partials[t] = sdata[t] - p;
}

__global__ __launch_bounds__(256) void scan3_kernel(int* __restrict__ rowptr,
                                                    const int* __restrict__ partials) {
    int t = threadIdx.x;
    int add = partials[blockIdx.x];
    int base = blockIdx.x * 1024 + t * 4;
#pragma unroll
    for (int j = 0; j < 4; j++)
        if (base + j < NN) rowptr[base + j] += add;
}

__global__ void scatter_kernel(const int* __restrict__ ei,
                               const int* __restrict__ rowptr,
                               int* __restrict__ cursor,
                               int* __restrict__ eidx,
                               int* __restrict__ esrc) {
    int e = blockIdx.x * blockDim.x + threadIdx.x;
    if (e >= EE) return;
    int d = ei[EE + e];
    int pos = rowptr[d] + atomicAdd(cursor + d, 1);
    eidx[pos] = e;
    esrc[pos] = ei[e];
}

// permute edge attrs into slot order: eaperm[p] = ea[eidx[p]]
__global__ __launch_bounds__(256) void permute_kernel(const float* __restrict__ ea,
                                                      const int* __restrict__ eidx,
                                                      float* __restrict__ eaperm) {
    int p4 = blockIdx.x * 16 + (threadIdx.x >> 4);
    if (p4 >= EE) return;
    int elem = threadIdx.x & 15;
    int e = eidx[p4];
    eaperm[(size_t)p4 * 16 + elem] = ea[(size_t)e * 16 + elem];
}

// ---------------- gather aggregation (no atomics, short chains) ----------------
__global__ __launch_bounds__(256) void agg_pass(const float* __restrict__ xin,
                                                const float* __restrict__ eaperm,
                                                const int* __restrict__ esrc,
                                                const float* __restrict__ ew,
                                                const float* __restrict__ eb,
                                                const int* __restrict__ rowptr,
                                                const int* __restrict__ cnt,
                                                float* __restrict__ agg) {
    const int lane = threadIdx.x & 63;
    int n = blockIdx.x * 4 + (threadIdx.x >> 6);
    if (n >= NN) return;

    float Wr[16];
#pragma unroll
    for (int k = 0; k < 16; k++) Wr[k] = ew[k * 64 + lane];
    const float br = eb[lane];

    int s   = __builtin_amdgcn_readfirstlane(rowptr[n]);
    int deg = __builtin_amdgcn_readfirstlane(cnt[n]);

    float sum = xin[(size_t)n * 64 + lane];

    for (int i = 0; i < deg; i += 2) {
        const bool two = (i + 1 < deg);
        const int p0 = s + i, p1 = s + i + 1;
        // uniform vector loads; values feed address math directly (no s-roundtrip)
        int s0 = esrc[p0];
        int s1 = two ? esrc[p1] : s0;
        const float4* q0 = (const float4*)(eaperm + (size_t)p0 * 16);
        const float4* q1 = (const float4*)(eaperm + (size_t)p1 * 16);
        float4 A0 = q0[0], A1 = q0[1], A2 = q0[2], A3 = q0[3];
        float4 B0, B1, B2, B3;
        if (two) { B0 = q1[0]; B1 = q1[1]; B2 = q1[2]; B3 = q1[3]; }
        float xv0 = xin[(size_t)s0 * 64 + lane];
        float xv1 = two ? xin[(size_t)s1 * 64 + lane] : 0.0f;

        float acc0 = br;
        acc0 += A0.x * Wr[0];  acc0 += A0.y * Wr[1];
        acc0 += A0.z * Wr[2];  acc0 += A0.w * Wr[3];
        acc0 += A1.x * Wr[4];  acc0 += A1.y * Wr[5];
        acc0 += A1.z * Wr[6];  acc0 += A1.w * Wr[7];
        acc0 += A2.x * Wr[8];  acc0 += A2.y * Wr[9];
        acc0 += A2.z * Wr[10]; acc0 += A2.w * Wr[11];
        acc0 += A3.x * Wr[12]; acc0 += A3.y * Wr[13];
        acc0 += A3.z * Wr[14]; acc0 += A3.w * Wr[15];
        sum += fmaxf(acc0 + xv0, 0.0f);
        if (two) {
            float acc1 = br;
            acc1 += B0.x * Wr[0];  acc1 += B0.y * Wr[1];
            acc1 += B0.z * Wr[2];  acc1 += B0.w * Wr[3];
            acc1 += B1.x * Wr[4];  acc1 += B1.y * Wr[5];
            acc1 += B1.z * Wr[6];  acc1 += B1.w * Wr[7];
            acc1 += B2.x * Wr[8];  acc1 += B2.y * Wr[9];
            acc1 += B2.z * Wr[10]; acc1 += B2.w * Wr[11];
            acc1 += B3.x * Wr[12]; acc1 += B3.y * Wr[13];
            acc1 += B3.z * Wr[14]; acc1 += B3.w * Wr[15];
            sum += fmaxf(acc1 + xv1, 0.0f);
        }
    }
    agg[(size_t)n * 64 + lane] = sum;
}

// ---------------- fused node-1 MLP: Y = relu( relu(X@W1+b1) @ W2 + b2 ) ------
__global__ __launch_bounds__(256) void node1_fused(const float* __restrict__ X,
                                                   const float* __restrict__ W1,
                                                   const float* __restrict__ B1,
                                                   const float* __restrict__ W2,
                                                   const float* __restrict__ B2,
                                                   float* __restrict__ Y,
                                                   int rows) {
    __shared__ float W1s[64 * 64];
    __shared__ float W2s[64 * 64];
    __shared__ float Hs[64 * 68];

    {
        const float4* s1 = (const float4*)W1;
        const float4* s2 = (const float4*)W2;
        float4* d1 = (float4*)W1s;
        float4* d2 = (float4*)W2s;
        for (int i = threadIdx.x; i < 1024; i += 256) { d1[i] = s1[i]; d2[i] = s2[i]; }
    }

    const int cg = threadIdx.x % 8;
    const int rg = threadIdx.x / 8;
    const int c0a = cg * 4, c0b = 32 + cg * 4;
    const int rbase = blockIdx.x * 64 + rg * 2;

    const float* xptr[2];
#pragma unroll
    for (int r = 0; r < 2; r++) {
        int rr = rbase + r;
        int ri = (rr < rows) ? rr : (rows - 1);
        xptr[r] = X + (size_t)ri * 64;
    }

    float acc[2][8];
    {
        const float4 v0 = *(const float4*)(B1 + c0a);
        const float4 v1 = *(const float4*)(B1 + c0b);
#pragma unroll
        for (int r = 0; r < 2; r++) {
            acc[r][0] = v0.x; acc[r][1] = v0.y; acc[r][2] = v0.z; acc[r][3] = v0.w;
            acc[r][4] = v1.x; acc[r][5] = v1.y; acc[r][6] = v1.z; acc[r][7] = v1.w;
        }
    }

    float4 a_cur[2], a_nxt[2];
#pragma unroll
    for (int r = 0; r < 2; r++) a_cur[r] = *(const float4*)(xptr[r]);

    __syncthreads();

#pragma unroll 2
    for (int k4 = 0; k4 < 64; k4 += 4) {
        if (k4 + 4 < 64) {
#pragma unroll
            for (int r = 0; r < 2; r++) a_nxt[r] = *(const float4*)(xptr[r] + k4 + 4);
        }
#pragma unroll
        for (int kk = 0; kk < 4; kk++) {
            const float4 w0 = *(const float4*)(W1s + (k4 + kk) * 64 + c0a);
            const float4 w1 = *(const float4*)(W1s + (k4 + kk) * 64 + c0b);
#pragma unroll
            for (int r = 0; r < 2; r++) {
                float av = (kk == 0) ? a_cur[r].x : (kk == 1) ? a_cur[r].y
                         : (kk == 2) ? a_cur[r].z : a_cur[r].w;
                acc[r][0] += av * w0.x; acc[r][1] += av * w0.y;
                acc[r][2] += av * w0.z; acc[r][3] += av * w0.w;
                acc[r][4] += av * w1.x; acc[r][5] += av * w1.y;
                acc[r][6] += av * w1.z; acc[r][7] += av * w1.w;
            }
        }
#pragma unroll
        for (int r = 0; r < 2; r++) a_cur[r] = a_nxt[r];
    }

#pragma unroll
    for (int r = 0; r < 2; r++) {
        const int lrow = rg * 2 + r;
        float4 v0, v1;
        v0.x = fmaxf(acc[r][0], 0.0f); v0.y = fmaxf(acc[r][1], 0.0f);
        v0.z = fmaxf(acc[r][2], 0.0f); v0.w = fmaxf(acc[r][3], 0.0f);
        v1.x = fmaxf(acc[r][4], 0.0f); v1.y = fmaxf(acc[r][5], 0.0f);
        v1.z = fmaxf(acc[r][6], 0.0f); v1.w = fmaxf(acc[r][7], 0.0f);
        *(float4*)(Hs + lrow * 68 + c0a) = v0;
        *(float4*)(Hs + lrow * 68 + c0b) = v1;
    }

    {
        const float4 v0 = *(const float4*)(B2 + c0a);
        const float4 v1 = *(const float4*)(B2 + c0b);
#pragma unroll
        for (int r = 0; r < 2; r++) {
            acc[r][0] = v0.x; acc[r][1] = v0.y; acc[r][2] = v0.z; acc[r][3] = v0.w;
            acc[r][4] = v1.x; acc[r][5] = v1.y; acc[r][6] = v1.z; acc[r][7] = v1.w;
        }
    }
    __syncthreads();

#pragma unroll 2
    for (int k4 = 0; k4 < 64; k4 += 4) {
        float4 a[2];
#pragma unroll
        for (int r = 0; r < 2; r++) a[r] = *(const float4*)(Hs + (rg * 2 + r) * 68 + k4);
#pragma unroll
        for (int kk = 0; kk < 4; kk++) {
            const float4 w0 = *(const float4*)(W2s + (k4 + kk) * 64 + c0a);
            const float4 w1 = *(const float4*)(W2s + (k4 + kk) * 64 + c0b);
#pragma unroll
            for (int r = 0; r < 2; r++) {
                float av = (kk == 0) ? a[r].x : (kk == 1) ? a[r].y
                         : (kk == 2) ? a[r].z : a[r].w;
                acc[r][0] += av * w0.x; acc[r][1] += av * w0.y;
                acc[r][2] += av * w0.z; acc[r][3] += av * w0.w;
                acc[r][4] += av * w1.x; acc[r][5] += av * w1.y;
                acc[r][6] += av * w1.z; acc[r][7] += av * w1.w;
            }
        }
    }

#pragma unroll
    for (int r = 0; r < 2; r++) {
        int rr = rbase + r;
        if (rr < rows) {
            float4 v0, v1;
            v0.x = fmaxf(acc[r][0], 0.0f); v0.y = fmaxf(acc[r][1], 0.0f);
            v0.z = fmaxf(acc[r][2], 0.0f); v0.w = fmaxf(acc[r][3], 0.0f);
            v1.x = fmaxf(acc[r][4], 0.0f); v1.y = fmaxf(acc[r][5], 0.0f);
            v1.z = fmaxf(acc[r][6], 0.0f); v1.w = fmaxf(acc[r][7], 0.0f);
            *(float4*)(Y + (size_t)rr * 64 + c0a) = v0;
            *(float4*)(Y + (size_t)rr * 64 + c0b) = v1;
        }
    }
}

// ---------------- n2a GEMM fused with graph pooling ----------------
// gsum[g] += sum over rows of graph g of relu(X[row]@W + B).  No H2 buffer.
// Block = 64 contiguous rows; sorted batch => graphs in block form a
// contiguous range [gfirst, glast]. Register run-reduce (4 rows/thread) ->
// LDS pool (span<=8) -> ~span*128 global atomics per block.
__global__ __launch_bounds__(256) void gemm_pool(const float* __restrict__ X,
                                                 const float* __restrict__ W,
                                                 const float* __restrict__ Bv,
                                                 const int* __restrict__ batch,
                                                 float* __restrict__ gsum,
                                                 int rows) {
    constexpr int K = 64, C = 128;
    constexpr int CPT = 8, RPT = 4, COLG = 16;
    constexpr int BR = 64;

    __shared__ float Bs[K * C];        // 32 KB
    __shared__ float pool[8 * C];      // 4 KB

    const int cg = threadIdx.x % COLG;
    const int rg = threadIdx.x / COLG;
    const int c0a = cg * 4;
    const int c0b = 64 + cg * 4;
    const int rbase = blockIdx.x * BR + rg * RPT;

    {
        const float4* wsrc = (const float4*)W;
        float4* wdst = (float4*)Bs;
        for (int i = threadIdx.x; i < K * C / 4; i += 256) wdst[i] = wsrc[i];
    }
    for (int i = threadIdx.x; i < 8 * C; i += 256) pool[i] = 0.0f;

    int r0 = blockIdx.x * BR; if (r0 > rows - 1) r0 = rows - 1;
    int r1 = blockIdx.x * BR + BR - 1; if (r1 > rows - 1) r1 = rows - 1;
    const int gfirst = batch[r0];
    const int glast  = batch[r1];
    const int span = glast - gfirst + 1;
    const bool useLds = (span <= 8);

    const float* xptr[RPT];
    int gid[RPT];
#pragma unroll
    for (int r = 0; r < RPT; r++) {
        int rr = rbase + r;
        int ri = (rr < rows) ? rr : (rows - 1);
        xptr[r] = X + (size_t)ri * K;
        gid[r] = batch[ri];
    }

    float acc[RPT][CPT];
    {
        const float4 v0 = *(const float4*)(Bv + c0a);
        const float4 v1 = *(const float4*)(Bv + c0b);
#pragma unroll
        for (int r = 0; r < RPT; r++) {
            acc[r][0] = v0.x; acc[r][1] = v0.y; acc[r][2] = v0.z; acc[r][3] = v0.w;
            acc[r][4] = v1.x; acc[r][5] = v1.y; acc[r][6] = v1.z; acc[r][7] = v1.w;
        }
    }

    float4 a_cur[RPT], a_nxt[RPT];
#pragma unroll
    for (int r = 0; r < RPT; r++) a_cur[r] = *(const float4*)(xptr[r]);

    __syncthreads();   // Bs staged, pool zeroed

#pragma unroll 2
    for (int k4 = 0; k4 < K; k4 += 4) {
        if (k4 + 4 < K) {
#pragma unroll
            for (int r = 0; r < RPT; r++) a_nxt[r] = *(const float4*)(xptr[r] + k4 + 4);
        }
#pragma unroll
        for (int kk = 0; kk < 4; kk++) {
            const float4 w0 = *(const float4*)(Bs + (k4 + kk) * C + c0a);
            const float4 w1 = *(const float4*)(Bs + (k4 + kk) * C + c0b);
#pragma unroll
            for (int r = 0; r < RPT; r++) {
                float av = (kk == 0) ? a_cur[r].x : (kk == 1) ? a_cur[r].y
                         : (kk == 2) ? a_cur[r].z : a_cur[r].w;
                acc[r][0] += av * w0.x; acc[r][1] += av * w0.y;
                acc[r][2] += av * w0.z; acc[r][3] += av * w0.w;
                acc[r][4] += av * w1.x; acc[r][5] += av * w1.y;
                acc[r][6] += av * w1.z; acc[r][7] += av * w1.w;
            }
        }
#pragma unroll
        for (int r = 0; r < RPT; r++) a_cur[r] = a_nxt[r];
    }

    // ---- register run-reduction over this thread's 4 consecutive rows ----
    float part[CPT];
    int curg = -1;
#pragma unroll 1
    for (int r = 0; r < RPT; r++) {
        int rr = rbase + r;
        if (rr >= rows) break;
        int g = gid[r];
        if (g != curg) {
            if (curg >= 0) {
                if (useLds) {
                    float* p = pool + (curg - gfirst) * C;
#pragma unroll
                    for (int j = 0; j < 4; j++) atomicAdd(p + c0a + j, part[j]);
#pragma unroll
                    for (int j = 0; j < 4; j++) atomicAdd(p + c0b + j, part[4 + j]);
                } else {
                    float* p = gsum + (size_t)curg * C;
#pragma unroll
                    for (int j = 0; j < 4; j++) atomicAdd(p + c0a + j, part[j]);
#pragma unroll
                    for (int j = 0; j < 4; j++) atomicAdd(p + c0b + j, part[4 + j]);
                }
            }
            curg = g;
#pragma unroll
            for (int j = 0; j < CPT; j++) part[j] = 0.0f;
        }
#pragma unroll
        for (int j = 0; j < CPT; j++) part[j] += fmaxf(acc[r][j], 0.0f);
    }
    if (curg >= 0) {
        if (useLds) {
            float* p = pool + (curg - gfirst) * C;
#pragma unroll
            for (int j = 0; j < 4; j++) atomicAdd(p + c0a + j, part[j]);
#pragma unroll
            for (int j = 0; j < 4; j++) atomicAdd(p + c0b + j, part[4 + j]);
        } else {
            float* p = gsum + (size_t)curg * C;
#pragma unroll
            for (int j = 0; j < 4; j++) atomicAdd(p + c0a + j, part[j]);
#pragma unroll
            for (int j = 0; j < 4; j++) atomicAdd(p + c0b + j, part[4 + j]);
        }
    }

    if (useLds) {
        __syncthreads();
        for (int i = threadIdx.x; i < span * C; i += 256) {
            float v = pool[i];
            if (v != 0.0f)
                atomicAdd(gsum + (size_t)(gfirst + (i >> 7)) * C + (i & 127), v);
        }
    }
}

// ---------------- head: m = gsum/cnt, emb = m@W2+b2 (commuted), 5-layer MLP ----
__global__ __launch_bounds__(128) void head_kernel(const float* __restrict__ gsum,
                                                   const int* __restrict__ se,
                                                   const float* __restrict__ usr,
                                                   const float* __restrict__ w2, const float* __restrict__ b2,
                                                   const float* __restrict__ h1w, const float* __restrict__ h1b,
                                                   const float* __restrict__ h2w, const float* __restrict__ h2b,
                                                   const float* __restrict__ h3w, const float* __restrict__ h3b,
                                                   const float* __restrict__ h4w, const float* __restrict__ h4b,
                                                   const float* __restrict__ h5w, const float* __restrict__ h5b,
                                                   float* __restrict__ out) {
    int g = blockIdx.x;
    int c = threadIdx.x;
    __shared__ float m[128];
    __shared__ float z0[140];
    __shared__ float z1[128];
    __shared__ float z2[64];
    __shared__ float z3[32];
    __shared__ float z4[16];

    int s = se[g], e = se[GG + g];
    float cnt = fmaxf((float)(e - s), 1.0f);
    m[c] = gsum[(size_t)g * 128 + c] / cnt;
    __syncthreads();

    {
        float acc = b2[c];
        for (int k = 0; k < 128; k++) acc += m[k] * w2[k * 128 + c];
        z0[c] = (e > s) ? acc : 0.0f;
    }
    if (c < 12) z0[128 + c] = usr[g * 12 + c];
    __syncthreads();

    {
        float acc = h1b[c];
        for (int k = 0; k < 140; k++) acc += z0[k] * h1w[k * 128 + c];
        z1[c] = fmaxf(acc, 0.0f);
    }
    __syncthreads();
    if (c < 64) {
        float acc = h2b[c];
        for (int k = 0; k < 128; k++) acc += z1[k] * h2w[k * 64 + c];
        z2[c] = fmaxf(acc, 0.0f);
    }
    __syncthreads();
    if (c < 32) {
        float acc = h3b[c];
        for (int k = 0; k < 64; k++) acc += z2[k] * h3w[k * 32 + c];
        z3[c] = fmaxf(acc, 0.0f);
    }
    __syncthreads();
    if (c < 16) {
        float acc = h4b[c];
        for (int k = 0; k < 32; k++) acc += z3[k] * h4w[k * 16 + c];
        z4[c] = fmaxf(acc, 0.0f);
    }
    __syncthreads();
    if (c == 0) {
        float acc = h5b[0];
        for (int k = 0; k < 16; k++) acc += z4[k] * h5w[k];
        out[g] = acc;
    }
}

extern "C" void kernel_launch(void* const* d_in, const int* in_sizes, int n_in,
                              void* d_out, int out_size, void* d_ws, size_t ws_size,
                              hipStream_t stream) {
    const float* x    = (const float*)d_in[0];
    const int*   ei   = (const int*)d_in[1];
    const float* ea   = (const float*)d_in[2];
    const int*   batch= (const int*)d_in[3];
    const float* usr  = (const float*)d_in[4];
    const float* e1w  = (const float*)d_in[5],  *e1b  = (const float*)d_in[6];
    const float* n1w1 = (const float*)d_in[7],  *n1b1 = (const float*)d_in[8];
    const float* n1w2 = (const float*)d_in[9],  *n1b2 = (const float*)d_in[10];
    const float* e2w  = (const float*)d_in[11], *e2b  = (const float*)d_in[12];
    const float* n2w1 = (const float*)d_in[13], *n2b1 = (const float*)d_in[14];
    const float* n2w2 = (const float*)d_in[15], *n2b2 = (const float*)d_in[16];
    const float* h1w  = (const float*)d_in[17], *h1b  = (const float*)d_in[18];
    const float* h2w  = (const float*)d_in[19], *h2b  = (const float*)d_in[20];
    const float* h3w  = (const float*)d_in[21], *h3b  = (const float*)d_in[22];
    const float* h4w  = (const float*)d_in[23], *h4b  = (const float*)d_in[24];
    const float* h5w  = (const float*)d_in[25], *h5b  = (const float*)d_in[26];

    float* w    = (float*)d_ws;
    float* agg  = w + AGG_OFF;
    float* h1   = w + H1_OFF;
    int*   se   = (int*)(w + SE_OFF);
    float* gsum = w + GSUM_OFF;

    int*   rowptr   = (int*)(w + CSR_OFF);
    int*   cursor   = rowptr + NN;
    int*   eidx     = cursor + NN;
    int*   esrc     = eidx + EE;
    int*   partials = esrc + EE;
    float* eaperm   = (float*)(partials + 256);

    hipMemsetAsync(se, 0, (size_t)GG * 2 * sizeof(int), stream);
    hipMemsetAsync(cursor, 0, (size_t)NN * sizeof(int), stream);
    hipMemsetAsync(gsum, 0, (size_t)GG * 128 * sizeof(float), stream);

    bounds_kernel<<<(NN + 255) / 256, 256, 0, stream>>>(batch, se);

    // ---- CSR build + slot-order edge materialization (shared by both layers) ----
    deg_kernel<<<(EE + 255) / 256, 256, 0, stream>>>(ei, cursor);
    scan1_kernel<<<NB1, 256, 0, stream>>>(cursor, rowptr, partials);
    scan2_kernel<<<1, 256, 0, stream>>>(partials);
    scan3_kernel<<<NB1, 256, 0, stream>>>(rowptr, partials);
    hipMemsetAsync(cursor, 0, (size_t)NN * sizeof(int), stream);
    scatter_kernel<<<(EE + 255) / 256, 256, 0, stream>>>(ei, rowptr, cursor, eidx, esrc);
    permute_kernel<<<(EE + 15) / 16, 256, 0, stream>>>(ea, eidx, eaperm);

    // ---- layer 1 ----
    agg_pass<<<(NN + 3) / 4, 256, 0, stream>>>(x, eaperm, esrc, e1w, e1b, rowptr, cursor, agg);
    node1_fused<<<(NN + 63) / 64, 256, 0, stream>>>(agg, n1w1, n1b1, n1w2, n1b2, h1, NN);

    // ---- layer 2 ----
    agg_pass<<<(NN + 3) / 4, 256, 0, stream>>>(h1, eaperm, esrc, e2w, e2b, rowptr, cursor, agg);
    // gsum[g] = sum over graph g of relu(agg @ n2w1 + n2b1); no H2 materialization
    gemm_pool<<<(NN + 63) / 64, 256, 0, stream>>>(agg, n2w1, n2b1, batch, gsum, NN);

    // ---- head ----
    head_kernel<<<GG, 128, 0, stream>>>(gsum, se, usr, n2w2, n2b2,
                                        h1w, h1b, h2w, h2b, h3w, h3b, h4w, h4b, h5w, h5b,
                                        (float*)d_out);
}